// Round 1
// baseline (351.485 us; speedup 1.0000x reference)
//
#include <hip/hip_runtime.h>
#include <stdint.h>

#define NG 6400
#define NN 64
#define NB 32
#define NA 3
#define NC 80

// output layout (floats)
#define BB_OFF  0ULL
#define SC_OFF  2457600ULL                 // NB*NA*NG*4
#define ANC_OFF 51609600ULL                // SC_OFF + NB*NA*NG*NC
#define FG_OFF  51609606ULL                // ANC_OFF + 6

// -------- kernel 1: per (b,n) top-3 nearest cells (stable (dist,idx) order) ----
__global__ __launch_bounds__(64) void topk_kernel(
    const float* __restrict__ grid,      // (NG,2)
    const float* __restrict__ gt_cxys,   // (NB,NN,2)
    const float* __restrict__ mask_gt,   // (NB,NN,NG) broadcast of valid
    int4* __restrict__ top3out)          // (NB*NN)
{
    const int row  = blockIdx.x;         // b*NN + n
    const int lane = threadIdx.x;
    const float cx = gt_cxys[row * 2 + 0];
    const float cy = gt_cxys[row * 2 + 1];

    unsigned long long k0 = ~0ULL, k1 = ~0ULL, k2 = ~0ULL;  // sorted ascending
    const float2* g2 = (const float2*)grid;
    #pragma unroll 4
    for (int i = 0; i < NG / 64; ++i) {
        int g = lane + i * 64;
        float2 gxy = g2[g];
        float d = fabsf((gxy.x + 0.5f) - cx) + fabsf((gxy.y + 0.5f) - cy);
        unsigned long long key =
            ((unsigned long long)__float_as_uint(d) << 13) | (unsigned)g;
        if (key < k2) {
            if (key < k1) { k2 = k1; if (key < k0) { k1 = k0; k0 = key; } else k1 = key; }
            else k2 = key;
        }
    }
    // butterfly merge of sorted triples across 64 lanes
    for (int off = 32; off; off >>= 1) {
        unsigned long long o0 = __shfl_xor(k0, off);
        unsigned long long o1 = __shfl_xor(k1, off);
        unsigned long long o2 = __shfl_xor(k2, off);
        unsigned long long a0 = k0, a1 = k1, a2 = k2, r0, r1, r2;
        if (a0 <= o0) {
            r0 = a0;
            if (a1 <= o0) { r1 = a1; r2 = (a2 <= o0) ? a2 : o0; }
            else          { r1 = o0; r2 = (a1 <= o1) ? a1 : o1; }
        } else {
            r0 = o0;
            if (o1 <= a0) { r1 = o1; r2 = (o2 <= a0) ? o2 : a0; }
            else          { r1 = a0; r2 = (o1 <= a1) ? o1 : a1; }
        }
        k0 = r0; k1 = r1; k2 = r2;
    }
    if (lane == 0) {
        bool valid = mask_gt[(size_t)row * NG] != 0.0f;
        int4 t;
        if (valid) { t.x = (int)(k0 & 8191u); t.y = (int)(k1 & 8191u); t.z = (int)(k2 & 8191u); }
        else       { t.x = t.y = t.z = -1; }
        t.w = 0;
        top3out[row] = t;
    }
}

// -------- kernel 2: per (b,g) resolve + write all outputs ----------------------
__global__ __launch_bounds__(256) void assign_kernel(
    const float* __restrict__ anc_wh,    // 6
    const float* __restrict__ grid,      // (NG,2)
    const int*   __restrict__ gt_labels, // (NB,NN)
    const float* __restrict__ gt_cxys,   // (NB,NN,2)
    const float* __restrict__ gt_whs,    // (NB,NN,2)
    const int4*  __restrict__ top3,      // (NB*NN)
    float* __restrict__ out)
{
    const int b   = blockIdx.y;
    const int g0  = blockIdx.x * 256;
    const int tid = threadIdx.x;
    const int g   = g0 + tid;

    __shared__ float scx[NN], scy[NN], sw[NN], sh[NN];
    __shared__ int   slab[NN];
    __shared__ int4  st3[NN];
    __shared__ int   slabel[256];

    if (tid < NN) {
        int r = b * NN + tid;
        scx[tid]  = gt_cxys[r * 2 + 0];
        scy[tid]  = gt_cxys[r * 2 + 1];
        sw[tid]   = gt_whs[r * 2 + 0];
        sh[tid]   = gt_whs[r * 2 + 1];
        slab[tid] = gt_labels[r];
        st3[tid]  = top3[r];
    }
    __syncthreads();

    float2 gxy = ((const float2*)grid)[g];
    const float gx = gxy.x, gy = gxy.y;

    unsigned long long mink = ~0ULL;
    int cnt = 0, claim = 0;
    #pragma unroll 8
    for (int n = 0; n < NN; ++n) {
        float d = fabsf((gx + 0.5f) - scx[n]) + fabsf((gy + 0.5f) - scy[n]);
        unsigned long long key =
            ((unsigned long long)__float_as_uint(d) << 6) | (unsigned)n;
        if (key < mink) mink = key;
        int4 t = st3[n];
        if (g == t.x || g == t.y || g == t.z) { if (cnt == 0) claim = n; ++cnt; }
    }

    int idx = 0; float fg = 0.0f;
    if (cnt == 1) { idx = claim; fg = 1.0f; }
    else if (cnt > 1) {
        int minn = (int)(mink & 63u);
        int4 t = st3[minn];
        if (g == t.x || g == t.y || g == t.z) { idx = minn; fg = 1.0f; }
    }

    const float tx = scx[idx] - gx, ty = scy[idx] - gy;
    const float w  = sw[idx],       h  = sh[idx];
    const int   lbl = slab[idx];
    slabel[tid] = lbl;

    // bboxes + fg per anchor
    #pragma unroll
    for (int na = 0; na < NA; ++na) {
        float aw = anc_wh[na * 2 + 0], ah = anc_wh[na * 2 + 1];
        float rw = w / aw, rh = h / ah;
        float m = fmaxf(fmaxf(rw, 1.0f / rw), fmaxf(rh, 1.0f / rh));
        bool ancok = m < 4.0f;
        size_t pos = (size_t)(b * NA + na) * NG + g;
        ((float4*)(out + BB_OFF))[pos] = make_float4(tx, ty, w, h);
        out[FG_OFF + pos] = (fg != 0.0f && ancok) ? 1.0f : 0.0f;
    }

    if (b == 0 && blockIdx.x == 0 && tid < 6) out[ANC_OFF + tid] = anc_wh[tid];

    __syncthreads();

    // one-hot scores: cooperative, fully-coalesced float4 fill
    #pragma unroll
    for (int na = 0; na < NA; ++na) {
        float4* base = (float4*)(out + SC_OFF + ((size_t)(b * NA + na) * NG + g0) * NC);
        #pragma unroll
        for (int it = 0; it < (256 * NC / 4) / 256; ++it) {
            int t = tid + it * 256;
            int gl = t / (NC / 4);
            int c0 = (t % (NC / 4)) * 4;
            int l  = slabel[gl];
            float4 v;
            v.x = (c0 == l) ? 1.0f : 0.0f;
            v.y = (c0 + 1 == l) ? 1.0f : 0.0f;
            v.z = (c0 + 2 == l) ? 1.0f : 0.0f;
            v.w = (c0 + 3 == l) ? 1.0f : 0.0f;
            base[t] = v;
        }
    }
}

extern "C" void kernel_launch(void* const* d_in, const int* in_sizes, int n_in,
                              void* d_out, int out_size, void* d_ws, size_t ws_size,
                              hipStream_t stream) {
    const float* anc_wh    = (const float*)d_in[0];
    const float* grid      = (const float*)d_in[1];
    const int*   gt_labels = (const int*)d_in[2];
    const float* gt_cxys   = (const float*)d_in[3];
    const float* gt_whs    = (const float*)d_in[4];
    const float* mask_gt   = (const float*)d_in[5];
    float* out = (float*)d_out;
    int4*  top3 = (int4*)d_ws;

    topk_kernel<<<dim3(NB * NN), 64, 0, stream>>>(grid, gt_cxys, mask_gt, top3);
    assign_kernel<<<dim3(NG / 256, NB), 256, 0, stream>>>(
        anc_wh, grid, gt_labels, gt_cxys, gt_whs, top3, out);
}

// Round 3
// 285.852 us; speedup vs baseline: 1.2296x; 1.2296x over previous
//
#include <hip/hip_runtime.h>
#include <stdint.h>

#define NG 6400
#define NN 64
#define NB 32
#define NA 3
#define NC 80

// output layout (floats)
#define BB_OFF  0ULL
#define SC_OFF  2457600ULL                 // NB*NA*NG*4
#define ANC_OFF 51609600ULL                // SC_OFF + NB*NA*NG*NC
#define FG_OFF  51609606ULL                // ANC_OFF + 6

typedef float vfloat4 __attribute__((ext_vector_type(4)));  // native vec for nontemporal

// -------- kernel 1: per (b,n) top-3 nearest cells (stable (dist,idx) order) ----
// 4 rows per block, one wave per row. float4 grid loads = 2 cells/load.
__global__ __launch_bounds__(256) void topk_kernel(
    const float* __restrict__ grid,      // (NG,2)
    const float* __restrict__ gt_cxys,   // (NB,NN,2)
    const float* __restrict__ mask_gt,   // (NB,NN,NG) broadcast of valid
    int4* __restrict__ top3out)          // (NB*NN)
{
    const int lane = threadIdx.x & 63;
    const int row  = blockIdx.x * 4 + (threadIdx.x >> 6);
    const float cx = gt_cxys[row * 2 + 0];
    const float cy = gt_cxys[row * 2 + 1];

    unsigned long long k0 = ~0ULL, k1 = ~0ULL, k2 = ~0ULL;  // sorted ascending
    const vfloat4* g4 = (const vfloat4*)grid;                // one float4 = 2 cells
    #pragma unroll 5
    for (int i = 0; i < NG / 128; ++i) {
        int p = lane + i * 64;
        vfloat4 xy = g4[p];
        int g = p * 2;
        float d0 = fabsf((xy.x + 0.5f) - cx) + fabsf((xy.y + 0.5f) - cy);
        float d1 = fabsf((xy.z + 0.5f) - cx) + fabsf((xy.w + 0.5f) - cy);
        unsigned long long key0 =
            ((unsigned long long)__float_as_uint(d0) << 13) | (unsigned)g;
        unsigned long long key1 =
            ((unsigned long long)__float_as_uint(d1) << 13) | (unsigned)(g + 1);
        if (key0 < k2) {
            if (key0 < k1) { k2 = k1; if (key0 < k0) { k1 = k0; k0 = key0; } else k1 = key0; }
            else k2 = key0;
        }
        if (key1 < k2) {
            if (key1 < k1) { k2 = k1; if (key1 < k0) { k1 = k0; k0 = key1; } else k1 = key1; }
            else k2 = key1;
        }
    }
    // butterfly merge of sorted triples across 64 lanes
    for (int off = 32; off; off >>= 1) {
        unsigned long long o0 = __shfl_xor(k0, off);
        unsigned long long o1 = __shfl_xor(k1, off);
        unsigned long long o2 = __shfl_xor(k2, off);
        unsigned long long a0 = k0, a1 = k1, a2 = k2, r0, r1, r2;
        if (a0 <= o0) {
            r0 = a0;
            if (a1 <= o0) { r1 = a1; r2 = (a2 <= o0) ? a2 : o0; }
            else          { r1 = o0; r2 = (a1 <= o1) ? a1 : o1; }
        } else {
            r0 = o0;
            if (o1 <= a0) { r1 = o1; r2 = (o2 <= a0) ? o2 : a0; }
            else          { r1 = a0; r2 = (o1 <= a1) ? o1 : a1; }
        }
        k0 = r0; k1 = r1; k2 = r2;
    }
    if (lane == 0) {
        bool valid = mask_gt[(size_t)row * NG] != 0.0f;
        int4 t;
        if (valid) { t.x = (int)(k0 & 8191u); t.y = (int)(k1 & 8191u); t.z = (int)(k2 & 8191u); }
        else       { t.x = t.y = t.z = -1; }
        t.w = 0;
        top3out[row] = t;
    }
}

// -------- kernel 2: per (b,g) resolve + write all outputs ----------------------
__global__ __launch_bounds__(256) void assign_kernel(
    const float* __restrict__ anc_wh,    // 6
    const float* __restrict__ grid,      // (NG,2)
    const int*   __restrict__ gt_labels, // (NB,NN)
    const float* __restrict__ gt_cxys,   // (NB,NN,2)
    const float* __restrict__ gt_whs,    // (NB,NN,2)
    const int4*  __restrict__ top3,      // (NB*NN)
    float* __restrict__ out)
{
    const int b   = blockIdx.y;
    const int g0  = blockIdx.x * 256;
    const int tid = threadIdx.x;
    const int g   = g0 + tid;

    __shared__ float scx[NN], scy[NN], sw[NN], sh[NN];
    __shared__ int   slab[NN];
    __shared__ int4  st3[NN];
    __shared__ int   slabel[256];

    if (tid < NN) {
        int r = b * NN + tid;
        scx[tid]  = gt_cxys[r * 2 + 0];
        scy[tid]  = gt_cxys[r * 2 + 1];
        sw[tid]   = gt_whs[r * 2 + 0];
        sh[tid]   = gt_whs[r * 2 + 1];
        slab[tid] = gt_labels[r];
        st3[tid]  = top3[r];
    }
    __syncthreads();

    float2 gxy = ((const float2*)grid)[g];
    const float px = gxy.x + 0.5f, py = gxy.y + 0.5f;

    // argmin over n (first-wins on ties == jnp.argmin) + claimant count
    float mind = 3.0e38f;
    int minn = 0, cnt = 0, claim = 0;
    #pragma unroll 8
    for (int n = 0; n < NN; ++n) {
        float d = fabsf(px - scx[n]) + fabsf(py - scy[n]);
        if (d < mind) { mind = d; minn = n; }
        int4 t = st3[n];
        bool hit = (g == t.x) || (g == t.y) || (g == t.z);
        if (hit) { if (cnt == 0) claim = n; ++cnt; }
    }

    int idx = 0; float fg = 0.0f;
    if (cnt == 1) { idx = claim; fg = 1.0f; }
    else if (cnt > 1) {
        int4 t = st3[minn];
        if (g == t.x || g == t.y || g == t.z) { idx = minn; fg = 1.0f; }
    }

    const float tx = scx[idx] - gxy.x, ty = scy[idx] - gxy.y;
    const float w  = sw[idx],          h  = sh[idx];
    slabel[tid] = slab[idx];

    // bboxes + fg per anchor (bbox identical across anchors; fg gated by ratio)
    #pragma unroll
    for (int na = 0; na < NA; ++na) {
        float aw = anc_wh[na * 2 + 0], ah = anc_wh[na * 2 + 1];
        float rw = w / aw, rh = h / ah;
        float m = fmaxf(fmaxf(rw, 1.0f / rw), fmaxf(rh, 1.0f / rh));
        size_t pos = (size_t)(b * NA + na) * NG + g;
        vfloat4 bb = {tx, ty, w, h};
        __builtin_nontemporal_store(bb, (vfloat4*)(out + BB_OFF) + pos);
        __builtin_nontemporal_store((fg != 0.0f && m < 4.0f) ? 1.0f : 0.0f,
                                    out + FG_OFF + pos);
    }

    if (b == 0 && blockIdx.x == 0 && tid < 6) out[ANC_OFF + tid] = anc_wh[tid];

    __syncthreads();

    // one-hot scores: cooperative, fully-coalesced float4 nontemporal fill
    #pragma unroll
    for (int na = 0; na < NA; ++na) {
        vfloat4* base = (vfloat4*)(out + SC_OFF) + ((size_t)(b * NA + na) * NG + g0) * (NC / 4);
        #pragma unroll 4
        for (int it = 0; it < (256 * NC / 4) / 256; ++it) {
            int t  = tid + it * 256;
            int gl = t / (NC / 4);
            int c0 = (t % (NC / 4)) * 4;
            int l  = slabel[gl];
            vfloat4 v;
            v.x = (c0     == l) ? 1.0f : 0.0f;
            v.y = (c0 + 1 == l) ? 1.0f : 0.0f;
            v.z = (c0 + 2 == l) ? 1.0f : 0.0f;
            v.w = (c0 + 3 == l) ? 1.0f : 0.0f;
            __builtin_nontemporal_store(v, base + t);
        }
    }
}

extern "C" void kernel_launch(void* const* d_in, const int* in_sizes, int n_in,
                              void* d_out, int out_size, void* d_ws, size_t ws_size,
                              hipStream_t stream) {
    const float* anc_wh    = (const float*)d_in[0];
    const float* grid      = (const float*)d_in[1];
    const int*   gt_labels = (const int*)d_in[2];
    const float* gt_cxys   = (const float*)d_in[3];
    const float* gt_whs    = (const float*)d_in[4];
    const float* mask_gt   = (const float*)d_in[5];
    float* out = (float*)d_out;
    int4*  top3 = (int4*)d_ws;

    topk_kernel<<<dim3(NB * NN / 4), 256, 0, stream>>>(grid, gt_cxys, mask_gt, top3);
    assign_kernel<<<dim3(NG / 256, NB), 256, 0, stream>>>(
        anc_wh, grid, gt_labels, gt_cxys, gt_whs, top3, out);
}

// Round 5
// 276.283 us; speedup vs baseline: 1.2722x; 1.0346x over previous
//
#include <hip/hip_runtime.h>
#include <stdint.h>

#define NG 6400
#define NN 64
#define NB 32
#define NA 3
#define NC 80

// output layout (floats)
#define BB_OFF  0ULL
#define SC_OFF  2457600ULL                 // NB*NA*NG*4
#define ANC_OFF 51609600ULL                // SC_OFF + NB*NA*NG*NC
#define FG_OFF  51609606ULL                // ANC_OFF + 6

typedef float vfloat4 __attribute__((ext_vector_type(4)));  // native vec for nontemporal

// -------- kernel 1: per (b,n) top-3 nearest cells (stable (dist,idx) order) ----
// 4 rows per block, one wave per row. No global loads in the scan loop:
// grid is a meshgrid, gx=(float)(g%80), gy=(float)(g/80) is bit-exact.
// NOTE: use plain /,% — compiler emits the CORRECT magic-mul (hand-rolled
// 3355443>>28 failed at g=80; off-by-one in the magic).
__global__ __launch_bounds__(256) void topk_kernel(
    const float* __restrict__ gt_cxys,   // (NB,NN,2)
    const float* __restrict__ mask_gt,   // (NB,NN,NG) broadcast of valid
    int4* __restrict__ top3out)          // (NB*NN)
{
    const int lane = threadIdx.x & 63;
    const int row  = blockIdx.x * 4 + (threadIdx.x >> 6);
    const float cx = gt_cxys[row * 2 + 0];
    const float cy = gt_cxys[row * 2 + 1];

    unsigned long long k0 = ~0ULL, k1 = ~0ULL, k2 = ~0ULL;  // sorted ascending
    #pragma unroll 4
    for (int i = 0; i < NG / 64; ++i) {
        unsigned g  = (unsigned)(lane + i * 64);
        unsigned iy = g / 80u;
        unsigned ix = g % 80u;
        float d = fabsf(((float)ix + 0.5f) - cx) + fabsf(((float)iy + 0.5f) - cy);
        unsigned long long key =
            ((unsigned long long)__float_as_uint(d) << 13) | g;
        if (key < k2) {
            if (key < k1) { k2 = k1; if (key < k0) { k1 = k0; k0 = key; } else k1 = key; }
            else k2 = key;
        }
    }
    // butterfly merge of sorted triples across 64 lanes
    for (int off = 32; off; off >>= 1) {
        unsigned long long o0 = __shfl_xor(k0, off);
        unsigned long long o1 = __shfl_xor(k1, off);
        unsigned long long o2 = __shfl_xor(k2, off);
        unsigned long long a0 = k0, a1 = k1, a2 = k2, r0, r1, r2;
        if (a0 <= o0) {
            r0 = a0;
            if (a1 <= o0) { r1 = a1; r2 = (a2 <= o0) ? a2 : o0; }
            else          { r1 = o0; r2 = (a1 <= o1) ? a1 : o1; }
        } else {
            r0 = o0;
            if (o1 <= a0) { r1 = o1; r2 = (o2 <= a0) ? o2 : a0; }
            else          { r1 = a0; r2 = (o1 <= a1) ? o1 : a1; }
        }
        k0 = r0; k1 = r1; k2 = r2;
    }
    if (lane == 0) {
        bool valid = mask_gt[(size_t)row * NG] != 0.0f;
        int4 t;
        if (valid) { t.x = (int)(k0 & 8191u); t.y = (int)(k1 & 8191u); t.z = (int)(k2 & 8191u); }
        else       { t.x = t.y = t.z = -1; }
        t.w = 0;
        top3out[row] = t;
    }
}

// -------- kernel 2: per (b,g) resolve + write all outputs ----------------------
__global__ __launch_bounds__(256) void assign_kernel(
    const float* __restrict__ anc_wh,    // 6
    const int*   __restrict__ gt_labels, // (NB,NN)
    const float* __restrict__ gt_cxys,   // (NB,NN,2)
    const float* __restrict__ gt_whs,    // (NB,NN,2)
    const int4*  __restrict__ top3,      // (NB*NN)
    float* __restrict__ out)
{
    const int b   = blockIdx.y;
    const int g0  = blockIdx.x * 256;
    const int tid = threadIdx.x;
    const int g   = g0 + tid;

    __shared__ float scx[NN], scy[NN], sw[NN], sh[NN];
    __shared__ int   slab[NN];
    __shared__ int4  st3[NN];
    __shared__ int   slabel[256];

    if (tid < NN) {
        int r = b * NN + tid;
        scx[tid]  = gt_cxys[r * 2 + 0];
        scy[tid]  = gt_cxys[r * 2 + 1];
        sw[tid]   = gt_whs[r * 2 + 0];
        sh[tid]   = gt_whs[r * 2 + 1];
        slab[tid] = gt_labels[r];
        st3[tid]  = top3[r];
    }
    __syncthreads();

    const unsigned iy = (unsigned)g / 80u;
    const unsigned ix = (unsigned)g % 80u;
    const float gx = (float)ix, gy = (float)iy;
    const float px = gx + 0.5f, py = gy + 0.5f;

    // argmin over n (first-wins on ties == jnp.argmin) + claimant count
    float mind = 3.0e38f;
    int minn = 0, cnt = 0, claim = 0;
    #pragma unroll 8
    for (int n = 0; n < NN; ++n) {
        float d = fabsf(px - scx[n]) + fabsf(py - scy[n]);
        if (d < mind) { mind = d; minn = n; }
        int4 t = st3[n];
        bool hit = (g == t.x) || (g == t.y) || (g == t.z);
        if (hit) { if (cnt == 0) claim = n; ++cnt; }
    }

    int idx = 0; float fg = 0.0f;
    if (cnt == 1) { idx = claim; fg = 1.0f; }
    else if (cnt > 1) {
        int4 t = st3[minn];
        if (g == t.x || g == t.y || g == t.z) { idx = minn; fg = 1.0f; }
    }

    const float tx = scx[idx] - gx, ty = scy[idx] - gy;
    const float w  = sw[idx],       h  = sh[idx];
    slabel[tid] = slab[idx];

    // bboxes + fg per anchor (bbox identical across anchors; fg gated by ratio)
    #pragma unroll
    for (int na = 0; na < NA; ++na) {
        float aw = anc_wh[na * 2 + 0], ah = anc_wh[na * 2 + 1];
        float rw = w / aw, rh = h / ah;
        float m = fmaxf(fmaxf(rw, 1.0f / rw), fmaxf(rh, 1.0f / rh));
        size_t pos = (size_t)(b * NA + na) * NG + g;
        vfloat4 bb = {tx, ty, w, h};
        __builtin_nontemporal_store(bb, (vfloat4*)(out + BB_OFF) + pos);
        __builtin_nontemporal_store((fg != 0.0f && m < 4.0f) ? 1.0f : 0.0f,
                                    out + FG_OFF + pos);
    }

    if (b == 0 && blockIdx.x == 0 && tid < 6) out[ANC_OFF + tid] = anc_wh[tid];

    __syncthreads();

    // one-hot scores: cooperative, fully-coalesced float4 nontemporal fill
    #pragma unroll
    for (int na = 0; na < NA; ++na) {
        vfloat4* base = (vfloat4*)(out + SC_OFF) + ((size_t)(b * NA + na) * NG + g0) * (NC / 4);
        #pragma unroll 4
        for (int it = 0; it < (256 * NC / 4) / 256; ++it) {
            int t  = tid + it * 256;
            int gl = t / (NC / 4);
            int c0 = (t % (NC / 4)) * 4;
            int l  = slabel[gl];
            vfloat4 v;
            v.x = (c0     == l) ? 1.0f : 0.0f;
            v.y = (c0 + 1 == l) ? 1.0f : 0.0f;
            v.z = (c0 + 2 == l) ? 1.0f : 0.0f;
            v.w = (c0 + 3 == l) ? 1.0f : 0.0f;
            __builtin_nontemporal_store(v, base + t);
        }
    }
}

extern "C" void kernel_launch(void* const* d_in, const int* in_sizes, int n_in,
                              void* d_out, int out_size, void* d_ws, size_t ws_size,
                              hipStream_t stream) {
    const float* anc_wh    = (const float*)d_in[0];
    const int*   gt_labels = (const int*)d_in[2];
    const float* gt_cxys   = (const float*)d_in[3];
    const float* gt_whs    = (const float*)d_in[4];
    const float* mask_gt   = (const float*)d_in[5];
    float* out = (float*)d_out;
    int4*  top3 = (int4*)d_ws;

    topk_kernel<<<dim3(NB * NN / 4), 256, 0, stream>>>(gt_cxys, mask_gt, top3);
    assign_kernel<<<dim3(NG / 256, NB), 256, 0, stream>>>(
        anc_wh, gt_labels, gt_cxys, gt_whs, top3, out);
}